// Round 1
// baseline (9141.682 us; speedup 1.0000x reference)
//
#include <hip/hip_runtime.h>

#define NCN 3000
#define NPN 30000
#define TT 8
#define EE 64000
#define HH 128

// ---------------- input projection: out[i,j] = b[j] + sum_k x[i,k]*w[j,k] ----
template<int K>
__global__ void linproj_kernel(const float* __restrict__ x, const float* __restrict__ w,
                               const float* __restrict__ b, float* __restrict__ out) {
    __shared__ float xs[K];
    int i = blockIdx.x;
    int j = threadIdx.x;
    if (j < K) xs[j] = x[(size_t)i * K + j];
    __syncthreads();
    float acc = b[j];
#pragma unroll
    for (int k = 0; k < K; ++k) acc = fmaf(xs[k], w[j * K + k], acc);
    out[(size_t)i * HH + j] = acc;
}

// ---------------- edge scatter: both directions in one pass ------------------
// sumP[ed[e]] += fc[es[e]];  sumC[es[e]] += fp[ed[e]];  counts once per t.
__global__ void scatter_kernel(const int* __restrict__ es, const int* __restrict__ ed,
                               const float* __restrict__ fc, const float* __restrict__ fp,
                               float* __restrict__ sumP, float* __restrict__ sumC,
                               float* __restrict__ cntP, float* __restrict__ cntC,
                               int do_count) {
    int e = blockIdx.x;
    int j = threadIdx.x;
    int s = es[e];
    int d = ed[e];
    atomicAdd(&sumP[(size_t)d * HH + j], fc[(size_t)s * HH + j]);
    atomicAdd(&sumC[(size_t)s * HH + j], fp[(size_t)d * HH + j]);
    if (do_count && j == 0) {
        atomicAdd(&cntP[d], 1.0f);
        atomicAdd(&cntC[s], 1.0f);
    }
}

// ---------------- SAGE linear: out = (msum/cnt) @ wl^T + bl + hin @ wr^T -----
// R rows per block, 128 threads (j = output channel).
template<int R>
__global__ void sage_kernel(const float* __restrict__ msum, const float* __restrict__ cnt,
                            const float* __restrict__ hin,
                            const float* __restrict__ wl, const float* __restrict__ bl,
                            const float* __restrict__ wr, float* __restrict__ out,
                            int relu) {
    __shared__ float ms[R][HH];
    __shared__ float hs[R][HH];
    int i0 = blockIdx.x * R;
    int j = threadIdx.x;
#pragma unroll
    for (int r = 0; r < R; ++r) {
        float inv = 1.0f / fmaxf(cnt[i0 + r], 1.0f);
        ms[r][j] = msum[(size_t)(i0 + r) * HH + j] * inv;
        hs[r][j] = hin[(size_t)(i0 + r) * HH + j];
    }
    __syncthreads();
    float acc[R];
#pragma unroll
    for (int r = 0; r < R; ++r) acc[r] = bl[j];
    for (int k = 0; k < HH; ++k) {
        float wlv = wl[j * HH + k];
        float wrv = wr[j * HH + k];
#pragma unroll
        for (int r = 0; r < R; ++r)
            acc[r] = fmaf(ms[r][k], wlv, fmaf(hs[r][k], wrv, acc[r]));
    }
#pragma unroll
    for (int r = 0; r < R; ++r) {
        float v = acc[r];
        if (relu) v = fmaxf(v, 0.0f);
        out[(size_t)(i0 + r) * HH + j] = v;
    }
}

// ---------------- GRU step (in-place h update), R rows per block -------------
template<int R>
__global__ void gru_kernel(const float* __restrict__ x,
                           const float* __restrict__ wih, const float* __restrict__ whh,
                           const float* __restrict__ bih, const float* __restrict__ bhh,
                           float* __restrict__ h) {
    __shared__ float xs[R][HH];
    __shared__ float hsm[R][HH];
    int i0 = blockIdx.x * R;
    int j = threadIdx.x;
#pragma unroll
    for (int r = 0; r < R; ++r) {
        xs[r][j]  = x[(size_t)(i0 + r) * HH + j];
        hsm[r][j] = h[(size_t)(i0 + r) * HH + j];
    }
    __syncthreads();
    float air[R], aiz[R], ain[R], ahr[R], ahz[R], ahn[R];
    float bir = bih[j], biz = bih[HH + j], bin_ = bih[2 * HH + j];
    float bhr = bhh[j], bhz = bhh[HH + j], bhn  = bhh[2 * HH + j];
#pragma unroll
    for (int r = 0; r < R; ++r) {
        air[r] = bir; aiz[r] = biz; ain[r] = bin_;
        ahr[r] = bhr; ahz[r] = bhz; ahn[r] = bhn;
    }
    for (int k = 0; k < HH; ++k) {
        float wir = wih[(0 * HH + j) * HH + k];
        float wiz = wih[(1 * HH + j) * HH + k];
        float win = wih[(2 * HH + j) * HH + k];
        float whr = whh[(0 * HH + j) * HH + k];
        float whz = whh[(1 * HH + j) * HH + k];
        float whn = whh[(2 * HH + j) * HH + k];
#pragma unroll
        for (int r = 0; r < R; ++r) {
            float xv = xs[r][k], hv = hsm[r][k];
            air[r] = fmaf(xv, wir, air[r]);
            aiz[r] = fmaf(xv, wiz, aiz[r]);
            ain[r] = fmaf(xv, win, ain[r]);
            ahr[r] = fmaf(hv, whr, ahr[r]);
            ahz[r] = fmaf(hv, whz, ahz[r]);
            ahn[r] = fmaf(hv, whn, ahn[r]);
        }
    }
#pragma unroll
    for (int r = 0; r < R; ++r) {
        float rg = 1.0f / (1.0f + __expf(-(air[r] + ahr[r])));
        float zg = 1.0f / (1.0f + __expf(-(aiz[r] + ahz[r])));
        float ng = tanhf(ain[r] + rg * ahn[r]);
        float hv = (1.0f - zg) * ng + zg * hsm[r][j];
        h[(size_t)(i0 + r) * HH + j] = hv;
    }
}

extern "C" void kernel_launch(void* const* d_in, const int* in_sizes, int n_in,
                              void* d_out, int out_size, void* d_ws, size_t ws_size,
                              hipStream_t stream) {
    const float* xc     = (const float*)d_in[0];   // [T,NC,32]
    const float* xp     = (const float*)d_in[1];   // [T,NP,64]
    const int*   esrc   = (const int*)d_in[2];     // [T,E]
    const int*   edst   = (const int*)d_in[3];     // [T,E]
    const float* w_clin = (const float*)d_in[4];
    const float* b_clin = (const float*)d_in[5];
    const float* w_plin = (const float*)d_in[6];
    const float* b_plin = (const float*)d_in[7];
    const float* wl1_cp = (const float*)d_in[8];
    const float* wr1_cp = (const float*)d_in[9];
    const float* wl1_pc = (const float*)d_in[10];
    const float* wr1_pc = (const float*)d_in[11];
    const float* wl2_cp = (const float*)d_in[12];
    const float* wr2_cp = (const float*)d_in[13];
    const float* wl2_pc = (const float*)d_in[14];
    const float* wr2_pc = (const float*)d_in[15];
    const float* bl1_cp = (const float*)d_in[16];
    const float* bl1_pc = (const float*)d_in[17];
    const float* bl2_cp = (const float*)d_in[18];
    const float* bl2_pc = (const float*)d_in[19];
    const float* w_ih_c = (const float*)d_in[20];
    const float* w_hh_c = (const float*)d_in[21];
    const float* w_ih_p = (const float*)d_in[22];
    const float* w_hh_p = (const float*)d_in[23];
    const float* b_ih_c = (const float*)d_in[24];
    const float* b_hh_c = (const float*)d_in[25];
    const float* b_ih_p = (const float*)d_in[26];
    const float* b_hh_p = (const float*)d_in[27];

    // workspace layout (floats): hp, hp1, hc, hc1, sumP, sumC, cntP, cntC
    float* ws   = (float*)d_ws;
    float* hp   = ws;                       // NP*128  (also reused as hp2)
    float* hp1  = hp  + (size_t)NPN * HH;   // NP*128
    float* hc   = hp1 + (size_t)NPN * HH;   // NC*128  (also reused as hc2)
    float* hc1  = hc  + (size_t)NCN * HH;   // NC*128
    float* sumP = hc1 + (size_t)NCN * HH;   // NP*128
    float* sumC = sumP + (size_t)NPN * HH;  // NC*128
    float* cntP = sumC + (size_t)NCN * HH;  // NP
    float* cntC = cntP + NPN;               // NC

    float* h_c = (float*)d_out;             // [NC,128]
    float* h_p = h_c + (size_t)NCN * HH;    // [NP,128]

    // GRU h0 = 0 (harness poisons d_out with 0xAA)
    hipMemsetAsync(d_out, 0, (size_t)out_size * sizeof(float), stream);

    for (int t = 0; t < TT; ++t) {
        const float* xct = xc + (size_t)t * NCN * 32;
        const float* xpt = xp + (size_t)t * NPN * 64;
        const int* es = esrc + (size_t)t * EE;
        const int* ed = edst + (size_t)t * EE;

        // zero sums + counts (contiguous region)
        hipMemsetAsync(sumP, 0,
                       ((size_t)NPN * HH + (size_t)NCN * HH + NPN + NCN) * sizeof(float),
                       stream);

        linproj_kernel<32><<<NCN, HH, 0, stream>>>(xct, w_clin, b_clin, hc);
        linproj_kernel<64><<<NPN, HH, 0, stream>>>(xpt, w_plin, b_plin, hp);

        scatter_kernel<<<EE, HH, 0, stream>>>(es, ed, hc, hp, sumP, sumC, cntP, cntC, 1);

        sage_kernel<8><<<NPN / 8, HH, 0, stream>>>(sumP, cntP, hp, wl1_cp, bl1_cp, wr1_cp, hp1, 1);
        sage_kernel<8><<<NCN / 8, HH, 0, stream>>>(sumC, cntC, hc, wl1_pc, bl1_pc, wr1_pc, hc1, 1);

        // zero sums only; counts are identical for layer 2 (same edge list)
        hipMemsetAsync(sumP, 0,
                       ((size_t)NPN * HH + (size_t)NCN * HH) * sizeof(float), stream);

        scatter_kernel<<<EE, HH, 0, stream>>>(es, ed, hc1, hp1, sumP, sumC, cntP, cntC, 0);

        sage_kernel<8><<<NPN / 8, HH, 0, stream>>>(sumP, cntP, hp1, wl2_cp, bl2_cp, wr2_cp, hp, 0);
        sage_kernel<8><<<NCN / 8, HH, 0, stream>>>(sumC, cntC, hc1, wl2_pc, bl2_pc, wr2_pc, hc, 0);

        gru_kernel<8><<<NPN / 8, HH, 0, stream>>>(hp, w_ih_p, w_hh_p, b_ih_p, b_hh_p, h_p);
        gru_kernel<8><<<NCN / 8, HH, 0, stream>>>(hc, w_ih_c, w_hh_c, b_ih_c, b_hh_c, h_c);
    }
}